// Round 14
// baseline (109.670 us; speedup 1.0000x reference)
//
#include <hip/hip_runtime.h>
#include <hip/hip_bf16.h>
#include <math.h>

// Problem constants
#define BB 32
#define TT 4096
#define CC 64
#define DD 512
#define NW 31          // number of windows
#define WIN 256
#define HOP 128
#define NROWS (BB * NW)   // 992

typedef float f32x4 __attribute__((ext_vector_type(4)));

// ---------------------------------------------------------------------------
// Kernel 1: band power via folded Goertzel. (round-4 version, measured 9.4us)
// ---------------------------------------------------------------------------
__global__ __launch_bounds__(512) void k_bandpower(const float* __restrict__ x,
                                                   float* __restrict__ feat) {
    __shared__ float lds[16384];         // 64 KB
    float* u = lds;                      // [128][64]
    float* v = lds + 8192;               // [128][64]

    const int tid = threadIdx.x;
    const int c   = tid & 63;
    const int g   = tid >> 6;            // wave id 0..7
    const int blk = blockIdx.x;          // 0..991
    const int b   = blk / NW;
    const int n   = blk % NW;

    // staged fold: read both halves once, write u,v (coalesced f32x4)
    const size_t winBase = ((size_t)b * TT + (size_t)n * HOP) * CC;
    const f32x4* h0 = (const f32x4*)(x + winBase);              // t = 0..127
    const f32x4* h1 = (const f32x4*)(x + winBase + 128 * CC);   // t = 128..255
    f32x4* u4 = (f32x4*)u;
    f32x4* v4 = (f32x4*)v;
    for (int i = tid; i < 2048; i += 512) {
        const f32x4 a  = h0[i];
        const f32x4 bb = h1[i];
        u4[i] = a + bb;
        v4[i] = a - bb;
    }
    __syncthreads();

    // 7 Goertzel chains per thread, 128 steps, on u (even f) or v (odd f)
    float coef[7], s1[7], s2[7];
#pragma unroll
    for (int j = 0; j < 7; ++j) {
        const int f = 1 + g + 8 * j;
        coef[j] = 2.0f * cospif((float)f * (1.0f / 128.0f)); // 2cos(2pi f/256)
        s1[j] = 0.0f;
        s2[j] = 0.0f;
    }
    // parity(f) = parity(1+g): g odd -> f even -> u; g even -> f odd -> v
    const float* src = ((g & 1) ? u : v) + c;

#pragma unroll 4
    for (int tt = 0; tt < 128; ++tt) {
        const float xv = src[tt * 64];
#pragma unroll
        for (int j = 0; j < 7; ++j) {
            const float sn = fmaf(coef[j], s1[j], xv - s2[j]);
            s2[j] = s1[j];
            s1[j] = sn;
        }
    }
    __syncthreads();   // done reading u/v; lds is re-aliased below

    // per-thread band sums
    float pb[5] = {0.0f, 0.0f, 0.0f, 0.0f, 0.0f};
#pragma unroll
    for (int j = 0; j < 7; ++j) {
        const int f = 1 + g + 8 * j;
        if (f > 50) continue;            // wave-uniform guard
        const float p = fmaf(s1[j], s1[j],
                        fmaf(s2[j], s2[j], -coef[j] * s1[j] * s2[j]));
        if (f <= 4)             pb[0] += p;
        if (f >= 4 && f <= 8)   pb[1] += p;
        if (f >= 8 && f <= 13)  pb[2] += p;
        if (f >= 13 && f <= 30) pb[3] += p;
        if (f >= 30)            pb[4] += p;
    }

    // cross-wave reduction via re-aliased LDS (each (g,k,c) written once)
    float (*bpart)[5][64] = (float (*)[5][64])lds;
#pragma unroll
    for (int k = 0; k < 5; ++k) bpart[g][k][c] = pb[k];
    __syncthreads();

    const float wband[5] = {1.0f / 4.0f, 1.0f / 5.0f, 1.0f / 6.0f,
                            1.0f / 18.0f, 1.0f / 21.0f};
    for (int idx = tid; idx < 320; idx += 512) {
        const int k  = idx >> 6;
        const int cc = idx & 63;
        float s = 0.0f;
#pragma unroll
        for (int gg = 0; gg < 8; ++gg) s += bpart[gg][k][cc];
        feat[(size_t)blk * 320 + idx] = s * wband[k];
    }
}

// ---------------------------------------------------------------------------
// Fused MLP + interp (round-7 structure, best measured: 97.8us), with
// NON-TEMPORAL stores in the span loop. Rationale: every timed replay runs
// right after a 1 GiB harness fill that leaves L2/L3 full of dirty foreign
// lines; plain stores must allocate 256 MiB of out-lines against dirty
// victims (eviction churn = the measured rep1-vs-warm gap in the REPS=3
// probe). NT stores skip L2/L3 allocation and write-combine to HBM.
// One block per (b, span i): 992 blocks; MLP rows i, i+1; load-free
// contiguous store stream (~132 rows = 264 KB per block).
// ---------------------------------------------------------------------------
__device__ __forceinline__ int i0_of(int t) {
    float pos = ((float)t + 0.5f) * (31.0f / 4096.0f) - 0.5f;
    pos = fminf(fmaxf(pos, 0.0f), 30.0f);
    return (int)pos;
}

__device__ __forceinline__ int span_start(int i) {
    if (i <= 0) return 0;
    if (i >= 31) return TT;
    int t = (int)(((float)i + 0.5f) * (4096.0f / 31.0f) - 0.5f) - 4;
    if (t < 0) t = 0;
    // first t with i0_of(t) >= i (monotone; guess is ~4 below the crossing)
    while (t < TT && i0_of(t) < i) ++t;
    return t;
}

__global__ __launch_bounds__(256) void k_mlp_interp(const float* __restrict__ feat,
                                                    const float* __restrict__ W1,
                                                    const float* __restrict__ b1,
                                                    const float* __restrict__ W2,
                                                    const float* __restrict__ b2,
                                                    float* __restrict__ out) {
    __shared__ float fs[2][320];
    __shared__ float hs[2][256];
    __shared__ float ABs[2][512];

    const int tid = threadIdx.x;
    const int blk = blockIdx.x;          // 0..991
    const int b   = blk / NW;
    const int i   = blk % NW;            // this block's i0 span
    const int r1  = min(i + 1, NW - 1);

    // stage the two feat rows
    const float* f0 = feat + ((size_t)b * NW + i) * 320;
    const float* f1 = feat + ((size_t)b * NW + r1) * 320;
    for (int k = tid; k < 320; k += 256) {
        fs[0][k] = f0[k];
        fs[1][k] = f1[k];
    }
    __syncthreads();

    // MLP phase 1: hidden (256), thread owns column tid, both rows
    {
        float a0 = b1[tid], a1 = a0;
        for (int k = 0; k < 320; ++k) {
            const float w = W1[(size_t)k * 256 + tid];
            a0 = fmaf(fs[0][k], w, a0);
            a1 = fmaf(fs[1][k], w, a1);
        }
        hs[0][tid] = fmaxf(a0, 0.0f);
        hs[1][tid] = fmaxf(a1, 0.0f);
    }
    __syncthreads();

    // MLP phase 2: output (512), thread owns columns tid and tid+256, both rows
    {
        float o00 = b2[tid], o01 = b2[tid + 256];
        float o10 = o00,     o11 = o01;
        for (int k = 0; k < 256; ++k) {
            const float w0 = W2[(size_t)k * 512 + tid];
            const float w1 = W2[(size_t)k * 512 + tid + 256];
            const float h0 = hs[0][k];
            const float h1 = hs[1][k];
            o00 = fmaf(h0, w0, o00);
            o01 = fmaf(h0, w1, o01);
            o10 = fmaf(h1, w0, o10);
            o11 = fmaf(h1, w1, o11);
        }
        ABs[0][tid] = o00; ABs[0][tid + 256] = o01;
        ABs[1][tid] = o10; ABs[1][tid + 256] = o11;
    }
    __syncthreads();

    // interp stream: res(t) = A + w(t) * (B - A), pure NT stores
    const int d4   = tid & 127;          // f32x4 slot within the 512-row
    const int half = tid >> 7;           // 0/1: even/odd t of each pair
    const f32x4 va = ((const f32x4*)ABs[0])[d4];
    const f32x4 vd = ((const f32x4*)ABs[1])[d4] - va;

    const int tS = span_start(i);
    const int tE = span_start(i + 1);

    for (int t = tS + half; t < tE; t += 2) {
        float pos = ((float)t + 0.5f) * (31.0f / 4096.0f) - 0.5f;
        pos = fminf(fmaxf(pos, 0.0f), 30.0f);
        const float w = pos - (float)i;
        const f32x4 res = va + w * vd;
        f32x4* o = (f32x4*)(out + ((size_t)b * TT + t) * DD);
        __builtin_nontemporal_store(res, &o[d4]);
    }
}

// ---------------------------------------------------------------------------
extern "C" void kernel_launch(void* const* d_in, const int* in_sizes, int n_in,
                              void* d_out, int out_size, void* d_ws, size_t ws_size,
                              hipStream_t stream) {
    const float* x  = (const float*)d_in[0];
    const float* W1 = (const float*)d_in[1];
    const float* b1 = (const float*)d_in[2];
    const float* W2 = (const float*)d_in[3];
    const float* b2 = (const float*)d_in[4];
    float* out = (float*)d_out;

    float* feat = (float*)d_ws;                  // NROWS*320 floats = 1.27 MB

    k_bandpower<<<NROWS, 512, 0, stream>>>(x, feat);
    k_mlp_interp<<<NROWS, 256, 0, stream>>>(feat, W1, b1, W2, b2, out);
}

// Round 15
// 99.934 us; speedup vs baseline: 1.0974x; 1.0974x over previous
//
#include <hip/hip_runtime.h>
#include <hip/hip_bf16.h>
#include <math.h>

// Problem constants
#define BB 32
#define TT 4096
#define CC 64
#define DD 512
#define NW 31          // number of windows
#define WIN 256
#define HOP 128
#define NROWS (BB * NW)   // 992

typedef float f32x4 __attribute__((ext_vector_type(4)));

// ---------------------------------------------------------------------------
// Kernel 1: band power via folded Goertzel. (round-4 version, measured 9.4us)
// ---------------------------------------------------------------------------
__global__ __launch_bounds__(512) void k_bandpower(const float* __restrict__ x,
                                                   float* __restrict__ feat) {
    __shared__ float lds[16384];         // 64 KB
    float* u = lds;                      // [128][64]
    float* v = lds + 8192;               // [128][64]

    const int tid = threadIdx.x;
    const int c   = tid & 63;
    const int g   = tid >> 6;            // wave id 0..7
    const int blk = blockIdx.x;          // 0..991
    const int b   = blk / NW;
    const int n   = blk % NW;

    // staged fold: read both halves once, write u,v (coalesced f32x4)
    const size_t winBase = ((size_t)b * TT + (size_t)n * HOP) * CC;
    const f32x4* h0 = (const f32x4*)(x + winBase);              // t = 0..127
    const f32x4* h1 = (const f32x4*)(x + winBase + 128 * CC);   // t = 128..255
    f32x4* u4 = (f32x4*)u;
    f32x4* v4 = (f32x4*)v;
    for (int i = tid; i < 2048; i += 512) {
        const f32x4 a  = h0[i];
        const f32x4 bb = h1[i];
        u4[i] = a + bb;
        v4[i] = a - bb;
    }
    __syncthreads();

    // 7 Goertzel chains per thread, 128 steps, on u (even f) or v (odd f)
    float coef[7], s1[7], s2[7];
#pragma unroll
    for (int j = 0; j < 7; ++j) {
        const int f = 1 + g + 8 * j;
        coef[j] = 2.0f * cospif((float)f * (1.0f / 128.0f)); // 2cos(2pi f/256)
        s1[j] = 0.0f;
        s2[j] = 0.0f;
    }
    // parity(f) = parity(1+g): g odd -> f even -> u; g even -> f odd -> v
    const float* src = ((g & 1) ? u : v) + c;

#pragma unroll 4
    for (int tt = 0; tt < 128; ++tt) {
        const float xv = src[tt * 64];
#pragma unroll
        for (int j = 0; j < 7; ++j) {
            const float sn = fmaf(coef[j], s1[j], xv - s2[j]);
            s2[j] = s1[j];
            s1[j] = sn;
        }
    }
    __syncthreads();   // done reading u/v; lds is re-aliased below

    // per-thread band sums
    float pb[5] = {0.0f, 0.0f, 0.0f, 0.0f, 0.0f};
#pragma unroll
    for (int j = 0; j < 7; ++j) {
        const int f = 1 + g + 8 * j;
        if (f > 50) continue;            // wave-uniform guard
        const float p = fmaf(s1[j], s1[j],
                        fmaf(s2[j], s2[j], -coef[j] * s1[j] * s2[j]));
        if (f <= 4)             pb[0] += p;
        if (f >= 4 && f <= 8)   pb[1] += p;
        if (f >= 8 && f <= 13)  pb[2] += p;
        if (f >= 13 && f <= 30) pb[3] += p;
        if (f >= 30)            pb[4] += p;
    }

    // cross-wave reduction via re-aliased LDS (each (g,k,c) written once)
    float (*bpart)[5][64] = (float (*)[5][64])lds;
#pragma unroll
    for (int k = 0; k < 5; ++k) bpart[g][k][c] = pb[k];
    __syncthreads();

    const float wband[5] = {1.0f / 4.0f, 1.0f / 5.0f, 1.0f / 6.0f,
                            1.0f / 18.0f, 1.0f / 21.0f};
    for (int idx = tid; idx < 320; idx += 512) {
        const int k  = idx >> 6;
        const int cc = idx & 63;
        float s = 0.0f;
#pragma unroll
        for (int gg = 0; gg < 8; ++gg) s += bpart[gg][k][cc];
        feat[(size_t)blk * 320 + idx] = s * wband[k];
    }
}

// ---------------------------------------------------------------------------
// Fused MLP + interp (round-7 structure) + per-block STAGGERED store start.
// Rationale: all prior variants advance their span stores in lockstep, so
// the instantaneous address set is {base_j + delta} with 264KB spacing --
// which aliases to a small subset of HBM channels under 2KB-granular
// channel hashing (132*j mod Nch cycles through 1/4 of channels). Rotating
// each block's start offset by a pseudo-random even amount decorrelates
// the streams (the fill kernel gets this for free from grid-striding).
// Grid: 1024 = 32 b x 32 jobs; job 0/1 = the two halves of span 0 (198
// rows, the straggler), jobs 2..31 = spans 1..30. Exactly 4 blocks/CU.
// Every t written exactly once; identical interp arithmetic (absmax ref 2.0).
// ---------------------------------------------------------------------------
__device__ __forceinline__ int i0_of(int t) {
    float pos = ((float)t + 0.5f) * (31.0f / 4096.0f) - 0.5f;
    pos = fminf(fmaxf(pos, 0.0f), 30.0f);
    return (int)pos;
}

__device__ __forceinline__ int span_start(int i) {
    if (i <= 0) return 0;
    if (i >= 31) return TT;
    int t = (int)(((float)i + 0.5f) * (4096.0f / 31.0f) - 0.5f) - 4;
    if (t < 0) t = 0;
    // first t with i0_of(t) >= i (monotone; guess is ~4 below the crossing)
    while (t < TT && i0_of(t) < i) ++t;
    return t;
}

__global__ __launch_bounds__(256) void k_mlp_interp(const float* __restrict__ feat,
                                                    const float* __restrict__ W1,
                                                    const float* __restrict__ b1,
                                                    const float* __restrict__ W2,
                                                    const float* __restrict__ b2,
                                                    float* __restrict__ out) {
    __shared__ float fs[2][320];
    __shared__ float hs[2][256];
    __shared__ float ABs[2][512];

    const int tid = threadIdx.x;
    const int blk = blockIdx.x;          // 0..1023
    const int b   = blk >> 5;            // batch
    const int job = blk & 31;            // 0..31
    const int i   = (job <= 1) ? 0 : (job - 1);   // span id
    const int r1  = min(i + 1, NW - 1);

    // stage the two feat rows
    const float* f0 = feat + ((size_t)b * NW + i) * 320;
    const float* f1 = feat + ((size_t)b * NW + r1) * 320;
    for (int k = tid; k < 320; k += 256) {
        fs[0][k] = f0[k];
        fs[1][k] = f1[k];
    }
    __syncthreads();

    // MLP phase 1: hidden (256), thread owns column tid, both rows
    {
        float a0 = b1[tid], a1 = a0;
        for (int k = 0; k < 320; ++k) {
            const float w = W1[(size_t)k * 256 + tid];
            a0 = fmaf(fs[0][k], w, a0);
            a1 = fmaf(fs[1][k], w, a1);
        }
        hs[0][tid] = fmaxf(a0, 0.0f);
        hs[1][tid] = fmaxf(a1, 0.0f);
    }
    __syncthreads();

    // MLP phase 2: output (512), thread owns columns tid and tid+256, both rows
    {
        float o00 = b2[tid], o01 = b2[tid + 256];
        float o10 = o00,     o11 = o01;
        for (int k = 0; k < 256; ++k) {
            const float w0 = W2[(size_t)k * 512 + tid];
            const float w1 = W2[(size_t)k * 512 + tid + 256];
            const float h0 = hs[0][k];
            const float h1 = hs[1][k];
            o00 = fmaf(h0, w0, o00);
            o01 = fmaf(h0, w1, o01);
            o10 = fmaf(h1, w0, o10);
            o11 = fmaf(h1, w1, o11);
        }
        ABs[0][tid] = o00; ABs[0][tid + 256] = o01;
        ABs[1][tid] = o10; ABs[1][tid + 256] = o11;
    }
    __syncthreads();

    // ---- compute this block's t-range [t0, t1) ----
    int t0, t1;
    if (job <= 1) {
        const int tE0 = span_start(1);               // 198
        const int mid = (tE0 >> 1) & ~1;             // even split point
        t0 = (job == 0) ? 0 : mid;
        t1 = (job == 0) ? mid : tE0;
    } else {
        t0 = span_start(i);
        t1 = span_start(i + 1);
    }
    const int len = t1 - t0;

    // per-block even rotation of the start point (decorrelate streams)
    const unsigned lenE = (unsigned)(len & ~1);
    const int rot = (int)((2u * (unsigned)(blk * 101 + (blk >> 3))) % lenE);
    const int tmid = t0 + rot;

    // interp stream: res(t) = A + w(t) * (B - A), pure stores, two segments
    const int d4   = tid & 127;          // f32x4 slot within the 512-row
    const int half = tid >> 7;           // 0/1: even/odd t of each pair
    const f32x4 va = ((const f32x4*)ABs[0])[d4];
    const f32x4 vd = ((const f32x4*)ABs[1])[d4] - va;
    const float fi = (float)i;

    for (int t = tmid + half; t < t1; t += 2) {
        float pos = ((float)t + 0.5f) * (31.0f / 4096.0f) - 0.5f;
        pos = fminf(fmaxf(pos, 0.0f), 30.0f);
        const float w = pos - fi;
        const f32x4 res = va + w * vd;
        f32x4* o = (f32x4*)(out + ((size_t)b * TT + t) * DD);
        o[d4] = res;
    }
    for (int t = t0 + half; t < tmid; t += 2) {
        float pos = ((float)t + 0.5f) * (31.0f / 4096.0f) - 0.5f;
        pos = fminf(fmaxf(pos, 0.0f), 30.0f);
        const float w = pos - fi;
        const f32x4 res = va + w * vd;
        f32x4* o = (f32x4*)(out + ((size_t)b * TT + t) * DD);
        o[d4] = res;
    }
}

// ---------------------------------------------------------------------------
extern "C" void kernel_launch(void* const* d_in, const int* in_sizes, int n_in,
                              void* d_out, int out_size, void* d_ws, size_t ws_size,
                              hipStream_t stream) {
    const float* x  = (const float*)d_in[0];
    const float* W1 = (const float*)d_in[1];
    const float* b1 = (const float*)d_in[2];
    const float* W2 = (const float*)d_in[3];
    const float* b2 = (const float*)d_in[4];
    float* out = (float*)d_out;

    float* feat = (float*)d_ws;                  // NROWS*320 floats = 1.27 MB

    k_bandpower<<<NROWS, 512, 0, stream>>>(x, feat);
    k_mlp_interp<<<BB * 32, 256, 0, stream>>>(feat, W1, b1, W2, b2, out);
}